// Round 1
// baseline (10988.069 us; speedup 1.0000x reference)
//
#include <hip/hip_runtime.h>
#include <math.h>

#define T_SEQ 2048
#define HID   5120
#define NH    16
#define DN    128
#define DR    64
#define DV    128
#define QL    1536
#define KVL   512
#define QKV_N (QL + KVL + DR)    // 2112
#define QB_N  (NH * (DN + DR))   // 3072
#define KVB_N (NH * (DN + DV))   // 4096
#define KFULL (KVL + DR)         // 576
#define OD    (NH * DV)          // 2048
#define SCALE_C 0.07216878364870322f       // (DN+DR)^-0.5
#define ROPE_K  0.28782313662425576f       // ln(10000)/32

// ---------------------------------------------------------------------------
// Generic f32 GEMM: C = A(MxK) @ B(KxN), row-major. M%128==0, K%16==0, N%4==0.
// 128x128 tile, BK=16, 256 threads, 8x8 micro-tile.
// ---------------------------------------------------------------------------
__global__ __launch_bounds__(256) void sgemm128(
    const float* __restrict__ A, const float* __restrict__ B,
    float* __restrict__ C, int M, int N, int K)
{
    __shared__ float As[16][132];   // [k][m], pad 132: transpose stores 2-way (free)
    __shared__ float Bs[16][132];   // [k][n]
    const int tid = threadIdx.x;
    const int bn = blockIdx.x * 128, bm = blockIdx.y * 128;
    const int tm = (tid >> 4) << 3, tn = (tid & 15) << 3;
    float acc[8][8];
#pragma unroll
    for (int i = 0; i < 8; ++i)
#pragma unroll
        for (int j = 0; j < 8; ++j) acc[i][j] = 0.f;

    for (int k0 = 0; k0 < K; k0 += 16) {
#pragma unroll
        for (int i = tid; i < 512; i += 256) {
            const int row = i >> 2, kq = (i & 3) << 2;
            const float4 a4 = *(const float4*)(A + (size_t)(bm + row) * K + k0 + kq);
            As[kq + 0][row] = a4.x; As[kq + 1][row] = a4.y;
            As[kq + 2][row] = a4.z; As[kq + 3][row] = a4.w;
        }
#pragma unroll
        for (int i = tid; i < 512; i += 256) {
            const int kk = i >> 5, nq = (i & 31) << 2;
            float4 b4 = make_float4(0.f, 0.f, 0.f, 0.f);
            if (bn + nq + 4 <= N)
                b4 = *(const float4*)(B + (size_t)(k0 + kk) * N + bn + nq);
            *(float4*)(&Bs[kk][nq]) = b4;
        }
        __syncthreads();
#pragma unroll
        for (int kk = 0; kk < 16; ++kk) {
            float a[8], b[8];
            *(float4*)(a)     = *(const float4*)(&As[kk][tm]);
            *(float4*)(a + 4) = *(const float4*)(&As[kk][tm + 4]);
            *(float4*)(b)     = *(const float4*)(&Bs[kk][tn]);
            *(float4*)(b + 4) = *(const float4*)(&Bs[kk][tn + 4]);
#pragma unroll
            for (int i = 0; i < 8; ++i)
#pragma unroll
                for (int j = 0; j < 8; ++j)
                    acc[i][j] = fmaf(a[i], b[j], acc[i][j]);
        }
        __syncthreads();
    }
#pragma unroll
    for (int i = 0; i < 8; ++i) {
        float* crow = C + (size_t)(bm + tm + i) * N + bn + tn;
        if (bn + tn + 4 <= N)
            *(float4*)(crow) = make_float4(acc[i][0], acc[i][1], acc[i][2], acc[i][3]);
        if (bn + tn + 8 <= N)
            *(float4*)(crow + 4) = make_float4(acc[i][4], acc[i][5], acc[i][6], acc[i][7]);
    }
}

// ---------------------------------------------------------------------------
// Fused: rmsnorm(q_a)->q_a_norm, rmsnorm(kv_a)->k_full[:,0:512],
//        rope(k_pe)->k_full[:,512:576].  One block per row t.
// ---------------------------------------------------------------------------
__global__ __launch_bounds__(256) void norm_rope_kernel(
    const float* __restrict__ qkv, const float* __restrict__ qa_w,
    const float* __restrict__ kva_w, const int* __restrict__ positions,
    float* __restrict__ q_a_norm, float* __restrict__ k_full)
{
    const int t = blockIdx.x, tid = threadIdx.x;
    const float* row = qkv + (size_t)t * QKV_N;
    float sq = 0.f, skv = 0.f;
    for (int i = tid; i < QL; i += 256)  { const float v = row[i];      sq  = fmaf(v, v, sq); }
    for (int i = tid; i < KVL; i += 256) { const float v = row[QL + i]; skv = fmaf(v, v, skv); }
#pragma unroll
    for (int off = 32; off >= 1; off >>= 1) {
        sq  += __shfl_down(sq, off, 64);
        skv += __shfl_down(skv, off, 64);
    }
    __shared__ float red[2][4];
    __shared__ float rs[2];
    const int wv = tid >> 6;
    if ((tid & 63) == 0) { red[0][wv] = sq; red[1][wv] = skv; }
    __syncthreads();
    if (tid == 0) {
        const float a = red[0][0] + red[0][1] + red[0][2] + red[0][3];
        const float b = red[1][0] + red[1][1] + red[1][2] + red[1][3];
        rs[0] = rsqrtf(a / (float)QL + 1e-6f);
        rs[1] = rsqrtf(b / (float)KVL + 1e-6f);
    }
    __syncthreads();
    const float rq = rs[0], rkv = rs[1];
    for (int i = tid; i < QL; i += 256)
        q_a_norm[(size_t)t * QL + i] = row[i] * rq * qa_w[i];
    for (int i = tid; i < KVL; i += 256)
        k_full[(size_t)t * KFULL + i] = row[QL + i] * rkv * kva_w[i];
    if (tid < 32) {
        const float pos = (float)positions[t];
        const float inv = expf(-(float)tid * ROPE_K);
        float s, c;
        sincosf(pos * inv, &s, &c);
        const float x1 = row[QL + KVL + 2 * tid];
        const float x2 = row[QL + KVL + 2 * tid + 1];
        k_full[(size_t)t * KFULL + KVL + 2 * tid]     = x1 * c - x2 * s;
        k_full[(size_t)t * KFULL + KVL + 2 * tid + 1] = x2 * c + x1 * s;
    }
}

// ---------------------------------------------------------------------------
// Per-head absorbed q_nope: qf[h][t][l] = SCALE * sum_d q[t,h*192+d] * w_kvb[l, h*256+d]
// NT batched GEMM: M=2048(t), N=512(l), K=128(d). 64x64 tile, BK=16, 4x4 micro.
// ---------------------------------------------------------------------------
__global__ __launch_bounds__(256) void gemm_qnope_kernel(
    const float* __restrict__ q, const float* __restrict__ w_kvb,
    float* __restrict__ qf)
{
    const int h = blockIdx.z;
    const int bn = blockIdx.x * 64;   // l
    const int bm = blockIdx.y * 64;   // t
    const int tid = threadIdx.x;
    __shared__ float As[16][68];
    __shared__ float Bs[16][68];
    const int tx = tid & 15, ty = tid >> 4;
    float acc[4][4];
#pragma unroll
    for (int i = 0; i < 4; ++i)
#pragma unroll
        for (int j = 0; j < 4; ++j) acc[i][j] = 0.f;

    const float* Abase = q + (size_t)bm * QB_N + h * (DN + DR);
    const float* Bbase = w_kvb + (size_t)bn * KVB_N + h * (DN + DV);
    const int row = tid >> 2, kq = (tid & 3) << 2;
    for (int k0 = 0; k0 < DN; k0 += 16) {
        {
            const float4 a4 = *(const float4*)(Abase + (size_t)row * QB_N + k0 + kq);
            As[kq + 0][row] = a4.x; As[kq + 1][row] = a4.y;
            As[kq + 2][row] = a4.z; As[kq + 3][row] = a4.w;
            const float4 b4 = *(const float4*)(Bbase + (size_t)row * KVB_N + k0 + kq);
            Bs[kq + 0][row] = b4.x; Bs[kq + 1][row] = b4.y;
            Bs[kq + 2][row] = b4.z; Bs[kq + 3][row] = b4.w;
        }
        __syncthreads();
#pragma unroll
        for (int kk = 0; kk < 16; ++kk) {
            float a[4], b[4];
            *(float4*)a = *(const float4*)(&As[kk][ty * 4]);
            *(float4*)b = *(const float4*)(&Bs[kk][tx * 4]);
#pragma unroll
            for (int i = 0; i < 4; ++i)
#pragma unroll
                for (int j = 0; j < 4; ++j)
                    acc[i][j] = fmaf(a[i], b[j], acc[i][j]);
        }
        __syncthreads();
    }
#pragma unroll
    for (int i = 0; i < 4; ++i)
#pragma unroll
        for (int j = 0; j < 4; ++j)
            qf[((size_t)h * T_SEQ + bm + ty * 4 + i) * KFULL + bn + tx * 4 + j] =
                acc[i][j] * SCALE_C;
}

// ---------------------------------------------------------------------------
// RoPE on q_pe -> qf[h][t][512:576], scaled by SCALE.
// ---------------------------------------------------------------------------
__global__ __launch_bounds__(256) void rope_qpe_kernel(
    const float* __restrict__ q, const int* __restrict__ positions,
    float* __restrict__ qf)
{
    const int t = blockIdx.x, tid = threadIdx.x;
    const float pos = (float)positions[t];
    for (int p = tid; p < NH * 32; p += 256) {
        const int h = p >> 5, i = p & 31;
        const float inv = expf(-(float)i * ROPE_K);
        float s, c;
        sincosf(pos * inv, &s, &c);
        const float* src = q + (size_t)t * QB_N + h * (DN + DR) + DN;
        float* dst = qf + ((size_t)h * T_SEQ + t) * KFULL + KVL;
        const float x1 = src[2 * i], x2 = src[2 * i + 1];
        dst[2 * i]     = SCALE_C * (x1 * c - x2 * s);
        dst[2 * i + 1] = SCALE_C * (x2 * c + x1 * s);
    }
}

// ---------------------------------------------------------------------------
// Flash attention per (head, 16-row Q tile) + fused w_vc epilogue.
// qf: (H, T, 576) pre-scaled. k_full: (T, 576); V = k_full[:, :512].
// o_mid: (T, H*128).
// ---------------------------------------------------------------------------
__global__ __launch_bounds__(256) void attn_kernel(
    const float* __restrict__ qf, const float* __restrict__ k_full,
    const float* __restrict__ w_kvb, float* __restrict__ o_mid)
{
    const int h = blockIdx.y;
    const int qt0 = blockIdx.x * 16;
    const int tid = threadIdx.x;
    __shared__ float qs[16 * KFULL];    // Q tile; reused as o_lat[16][516] at end
    __shared__ float st[16][33];        // score/prob tile (pad 33: conflict-free)
    __shared__ float m_run[16], l_run[16], alpha_s[16];

    const float* qsrc = qf + ((size_t)h * T_SEQ + qt0) * KFULL;
    for (int i = tid * 4; i < 16 * KFULL; i += 1024)
        *(float4*)(qs + i) = *(const float4*)(qsrc + i);
    if (tid < 16) { m_run[tid] = -1e30f; l_run[tid] = 0.f; }
    const int r2 = tid >> 4, c4 = tid & 15;   // phase-2: row, col-group
    const int j1 = tid & 31, rg = tid >> 5;   // phase-1: col, row-group
    float4 oa[8];
#pragma unroll
    for (int u = 0; u < 8; ++u) oa[u] = make_float4(0.f, 0.f, 0.f, 0.f);
    __syncthreads();

    for (int k0 = 0; k0 < qt0 + 16; k0 += 32) {
        // ---- phase 1: S = Q K^T (Q pre-scaled), causal mask ----
        {
            const int jg = k0 + j1;
            const float* kr = k_full + (size_t)jg * KFULL;
            const float* q0 = qs + rg * KFULL;
            const float* q1 = qs + (rg + 8) * KFULL;
            float acc0 = 0.f, acc1 = 0.f;
            for (int d = 0; d < KFULL; d += 4) {
                const float4 k4 = *(const float4*)(kr + d);
                const float4 a4 = *(const float4*)(q0 + d);
                const float4 b4 = *(const float4*)(q1 + d);
                acc0 = fmaf(a4.x, k4.x, fmaf(a4.y, k4.y, fmaf(a4.z, k4.z, fmaf(a4.w, k4.w, acc0))));
                acc1 = fmaf(b4.x, k4.x, fmaf(b4.y, k4.y, fmaf(b4.z, k4.z, fmaf(b4.w, k4.w, acc1))));
            }
            st[rg][j1]     = (jg <= qt0 + rg)     ? acc0 : -1e30f;
            st[rg + 8][j1] = (jg <= qt0 + rg + 8) ? acc1 : -1e30f;
        }
        __syncthreads();
        // ---- online softmax update (one thread per row) ----
        if (tid < 16) {
            const int r = tid;
            const float m_old = m_run[r];
            float mloc = m_old;
#pragma unroll
            for (int j = 0; j < 32; ++j) mloc = fmaxf(mloc, st[r][j]);
            const float alpha = expf(m_old - mloc);
            float sum = 0.f;
#pragma unroll
            for (int j = 0; j < 32; ++j) {
                const float p = expf(st[r][j] - mloc);
                st[r][j] = p;
                sum += p;
            }
            l_run[r] = l_run[r] * alpha + sum;
            m_run[r] = mloc;
            alpha_s[r] = alpha;
        }
        __syncthreads();
        // ---- phase 2: O += P V ----
        {
            const float alpha = alpha_s[r2];
#pragma unroll
            for (int u = 0; u < 8; ++u) {
                oa[u].x *= alpha; oa[u].y *= alpha; oa[u].z *= alpha; oa[u].w *= alpha;
            }
            for (int j = 0; j < 32; ++j) {
                const float p = st[r2][j];
                const float* vr = k_full + (size_t)(k0 + j) * KFULL;
#pragma unroll
                for (int u = 0; u < 8; ++u) {
                    const float4 v = *(const float4*)(vr + (c4 + 16 * u) * 4);
                    oa[u].x = fmaf(p, v.x, oa[u].x);
                    oa[u].y = fmaf(p, v.y, oa[u].y);
                    oa[u].z = fmaf(p, v.z, oa[u].z);
                    oa[u].w = fmaf(p, v.w, oa[u].w);
                }
            }
        }
        __syncthreads();
    }
    // ---- normalize, stash o_lat in LDS (stride 516: 2-way banks, 16B aligned) ----
    {
        const float linv = 1.f / l_run[r2];
#pragma unroll
        for (int u = 0; u < 8; ++u) {
            float4 v = oa[u];
            v.x *= linv; v.y *= linv; v.z *= linv; v.w *= linv;
            *(float4*)(qs + r2 * 516 + (c4 + 16 * u) * 4) = v;
        }
    }
    __syncthreads();
    // ---- epilogue: o[t, h*128+v] = o_lat @ w_vc[:,h,:] ----
    {
        const int r3 = tid >> 4, vg = tid & 15;
        float acc8[8];
#pragma unroll
        for (int v = 0; v < 8; ++v) acc8[v] = 0.f;
        const float* wbase = w_kvb + h * (DN + DV) + DN + vg * 8;
        const float* olrow = qs + r3 * 516;
        for (int l = 0; l < KVL; ++l) {
            const float ol = olrow[l];
            const float* wr = wbase + (size_t)l * KVB_N;
#pragma unroll
            for (int v = 0; v < 8; ++v) acc8[v] = fmaf(ol, wr[v], acc8[v]);
        }
        float* orow = o_mid + (size_t)(qt0 + r3) * OD + h * DV + vg * 8;
#pragma unroll
        for (int v = 0; v < 8; ++v) orow[v] = acc8[v];
    }
}

// ---------------------------------------------------------------------------
extern "C" void kernel_launch(void* const* d_in, const int* in_sizes, int n_in,
                              void* d_out, int out_size, void* d_ws, size_t ws_size,
                              hipStream_t stream)
{
    const int*   positions = (const int*)d_in[0];
    const float* hs        = (const float*)d_in[1];
    const float* w_fused   = (const float*)d_in[2];
    const float* w_qb      = (const float*)d_in[3];
    const float* w_kvb     = (const float*)d_in[4];
    const float* w_o       = (const float*)d_in[5];
    const float* qa_w      = (const float*)d_in[6];
    const float* kva_w     = (const float*)d_in[7];
    float* out = (float*)d_out;
    float* ws  = (float*)d_ws;

    // workspace layout (floats)
    float* qf     = ws;                                   // 16*2048*576 = 18,874,368
    float* kfull  = qf + (size_t)NH * T_SEQ * KFULL;      //  2048*576   =  1,179,648
    float* o_mid  = kfull + (size_t)T_SEQ * KFULL;        //  2048*2048  =  4,194,304
    float* qkv    = o_mid + (size_t)T_SEQ * OD;           //  region A (qkv then q): 6,291,456
    float* qmat   = qkv;                                  //  alias: qkv dead after norm_rope
    float* qanorm = qkv + (size_t)T_SEQ * QB_N;           //  2048*1536  =  3,145,728
    // total = 33,685,504 floats = ~135 MB

    // 1. qkv = hs @ w_fused
    sgemm128<<<dim3((QKV_N + 127) / 128, T_SEQ / 128), 256, 0, stream>>>(
        hs, w_fused, qkv, T_SEQ, QKV_N, HID);
    // 2. rmsnorms + k_pe rope
    norm_rope_kernel<<<T_SEQ, 256, 0, stream>>>(
        qkv, qa_w, kva_w, positions, qanorm, kfull);
    // 3. q = q_a_norm @ w_qb
    sgemm128<<<dim3(QB_N / 128, T_SEQ / 128), 256, 0, stream>>>(
        qanorm, w_qb, qmat, T_SEQ, QB_N, QL);
    // 4. absorbed q_nope (per head), pre-scaled
    gemm_qnope_kernel<<<dim3(KVL / 64, T_SEQ / 64, NH), 256, 0, stream>>>(
        qmat, w_kvb, qf);
    // 5. q_pe rope, pre-scaled
    rope_qpe_kernel<<<T_SEQ, 256, 0, stream>>>(qmat, positions, qf);
    // 6. flash attention + w_vc epilogue
    attn_kernel<<<dim3(T_SEQ / 16, NH), 256, 0, stream>>>(
        qf, kfull, w_kvb, o_mid);
    // 7. out = o_mid @ w_o
    sgemm128<<<dim3(HID / 128, T_SEQ / 128), 256, 0, stream>>>(
        o_mid, w_o, out, T_SEQ, HID, OD);
}

// Round 2
// 1016.437 us; speedup vs baseline: 10.8104x; 10.8104x over previous
//
#include <hip/hip_runtime.h>
#include <math.h>

typedef unsigned short u16;
typedef __bf16 v8bf __attribute__((ext_vector_type(8)));
typedef float   v4f  __attribute__((ext_vector_type(4)));

#define T_SEQ 2048
#define HID   5120
#define NH    16
#define DN    128
#define DR    64
#define DV    128
#define QL    1536
#define KVL   512
#define QKV_N (QL + KVL + DR)    // 2112
#define QB_N  (NH * (DN + DR))   // 3072
#define KVB_N (NH * (DN + DV))   // 4096
#define KFULL (KVL + DR)         // 576
#define OD    (NH * DV)          // 2048
#define SCALE_C 0.07216878364870322f       // (DN+DR)^-0.5
#define ROPE_K  0.28782313662425576f       // ln(10000)/32

__device__ __forceinline__ u16 f2b(float f) {
    unsigned int u = __float_as_uint(f);
    return (u16)((u + 0x7fffu + ((u >> 16) & 1u)) >> 16);
}

#if __has_builtin(__builtin_amdgcn_global_load_lds)
#define ASYNC_CP16(gp, lp) __builtin_amdgcn_global_load_lds( \
    (__attribute__((address_space(1))) void*)(gp),           \
    (__attribute__((address_space(3))) void*)(lp), 16, 0, 0)
#else
#define ASYNC_CP16(gp, lp) do { *(uint4*)(lp) = *(const uint4*)(gp); } while (0)
#endif

// ---------------------------------------------------------------------------
// f32 -> bf16 elementwise (n4 = count/4)
// ---------------------------------------------------------------------------
__global__ __launch_bounds__(256) void cvt_bf16(
    const float* __restrict__ in, u16* __restrict__ out, int n4)
{
    int i = blockIdx.x * 256 + threadIdx.x;
    if (i < n4) {
        float4 v = ((const float4*)in)[i];
        ushort4 o;
        o.x = f2b(v.x); o.y = f2b(v.y); o.z = f2b(v.z); o.w = f2b(v.w);
        ((ushort4*)out)[i] = o;
    }
}

// ---------------------------------------------------------------------------
// Transpose+convert: out[n][k] (bf16, row stride Kd) = in[k][col0+z*zcol+n] (f32)
// grid: (Kd/32, Nd/32, Z); 256 threads; 32x32 tiles.
// ---------------------------------------------------------------------------
__global__ __launch_bounds__(256) void transcvt(
    const float* __restrict__ in, u16* __restrict__ out,
    int ldin, int col0, int zcol, long out_z, int Kd)
{
    __shared__ u16 tile[32][33];
    const int bk = blockIdx.x * 32, bn = blockIdx.y * 32, z = blockIdx.z;
    const int r = threadIdx.x >> 3, cg = (threadIdx.x & 7) * 4;
    const float4 v = *(const float4*)(in + (size_t)(bk + r) * ldin + col0 + (size_t)z * zcol + bn + cg);
    tile[r][cg + 0] = f2b(v.x); tile[r][cg + 1] = f2b(v.y);
    tile[r][cg + 2] = f2b(v.z); tile[r][cg + 3] = f2b(v.w);
    __syncthreads();
    ushort4 o;
    o.x = tile[cg + 0][r]; o.y = tile[cg + 1][r];
    o.z = tile[cg + 2][r]; o.w = tile[cg + 3][r];
    *(ushort4*)(out + (size_t)z * out_z + (size_t)(bn + r) * Kd + bk + cg) = o;
}

// ---------------------------------------------------------------------------
// bf16 MFMA GEMM (m97-style): C(f32, MxN) = A(bf16 MxK) * Bt(bf16 NxK)^T
// 128x128 tile, BK=32, 256 thr, 4 waves each 64x64 (4x4 x 16x16x32 frags).
// M%128==0, K%32==0; N guarded on store (Bt rows must be allocated to 128-mult).
// ---------------------------------------------------------------------------
__global__ __launch_bounds__(256, 2) void gemm_bt(
    const u16* __restrict__ A, const u16* __restrict__ Bt,
    float* __restrict__ C, int M, int N, int K)
{
    __shared__ u16 As[128 * 32], Bs[128 * 32];
    const int tid = threadIdx.x, lane = tid & 63, wave = tid >> 6;
    const int g = lane >> 4, l15 = lane & 15;
    const int bm = blockIdx.y * 128, bn = blockIdx.x * 128;
    const int wm = (wave & 1) * 64, wn = (wave >> 1) * 64;
    const int srow = tid >> 2, skq = (tid & 3) * 8;   // staging: row 0..63, k-chunk
    v4f acc[4][4];
#pragma unroll
    for (int i = 0; i < 4; ++i)
#pragma unroll
        for (int j = 0; j < 4; ++j) acc[i][j] = (v4f){0.f, 0.f, 0.f, 0.f};

    for (int k0 = 0; k0 < K; k0 += 32) {
        ASYNC_CP16(A  + (size_t)(bm + srow) * K + k0 + skq,      &As[tid * 8]);
        ASYNC_CP16(A  + (size_t)(bm + 64 + srow) * K + k0 + skq, &As[2048 + tid * 8]);
        ASYNC_CP16(Bt + (size_t)(bn + srow) * K + k0 + skq,      &Bs[tid * 8]);
        ASYNC_CP16(Bt + (size_t)(bn + 64 + srow) * K + k0 + skq, &Bs[2048 + tid * 8]);
        __syncthreads();
        v8bf af[4], bq[4];
#pragma unroll
        for (int mi = 0; mi < 4; ++mi) af[mi] = *(const v8bf*)&As[(wm + mi * 16 + l15) * 32 + g * 8];
#pragma unroll
        for (int ni = 0; ni < 4; ++ni) bq[ni] = *(const v8bf*)&Bs[(wn + ni * 16 + l15) * 32 + g * 8];
#pragma unroll
        for (int mi = 0; mi < 4; ++mi)
#pragma unroll
            for (int ni = 0; ni < 4; ++ni)
                acc[mi][ni] = __builtin_amdgcn_mfma_f32_16x16x32_bf16(af[mi], bq[ni], acc[mi][ni], 0, 0, 0);
        __syncthreads();
    }
#pragma unroll
    for (int mi = 0; mi < 4; ++mi)
#pragma unroll
        for (int ni = 0; ni < 4; ++ni) {
            const int col = bn + wn + ni * 16 + l15;
            if (col < N) {
#pragma unroll
                for (int r = 0; r < 4; ++r)
                    C[(size_t)(bm + wm + mi * 16 + g * 4 + r) * N + col] = acc[mi][ni][r];
            }
        }
}

// ---------------------------------------------------------------------------
// Batched per-head w_vc GEMM: o_mid[t][h*128+v] (bf16) = o_lat_h(2048x512) @ wvcT_h(128x512)^T
// grid (16, NH).
// ---------------------------------------------------------------------------
__global__ __launch_bounds__(256, 2) void gemm_vc(
    const u16* __restrict__ o_lat, const u16* __restrict__ wvcT,
    u16* __restrict__ o_mid)
{
    __shared__ u16 As[128 * 32], Bs[128 * 32];
    const int tid = threadIdx.x, lane = tid & 63, wave = tid >> 6;
    const int g = lane >> 4, l15 = lane & 15;
    const int h = blockIdx.y;
    const int bm = blockIdx.x * 128;
    const u16* A  = o_lat + (size_t)h * T_SEQ * 512;
    const u16* Bt = wvcT + (size_t)h * 128 * 512;
    const int wm = (wave & 1) * 64, wn = (wave >> 1) * 64;
    const int srow = tid >> 2, skq = (tid & 3) * 8;
    v4f acc[4][4];
#pragma unroll
    for (int i = 0; i < 4; ++i)
#pragma unroll
        for (int j = 0; j < 4; ++j) acc[i][j] = (v4f){0.f, 0.f, 0.f, 0.f};

    for (int k0 = 0; k0 < 512; k0 += 32) {
        ASYNC_CP16(A  + (size_t)(bm + srow) * 512 + k0 + skq,      &As[tid * 8]);
        ASYNC_CP16(A  + (size_t)(bm + 64 + srow) * 512 + k0 + skq, &As[2048 + tid * 8]);
        ASYNC_CP16(Bt + (size_t)(srow) * 512 + k0 + skq,           &Bs[tid * 8]);
        ASYNC_CP16(Bt + (size_t)(64 + srow) * 512 + k0 + skq,      &Bs[2048 + tid * 8]);
        __syncthreads();
        v8bf af[4], bq[4];
#pragma unroll
        for (int mi = 0; mi < 4; ++mi) af[mi] = *(const v8bf*)&As[(wm + mi * 16 + l15) * 32 + g * 8];
#pragma unroll
        for (int ni = 0; ni < 4; ++ni) bq[ni] = *(const v8bf*)&Bs[(wn + ni * 16 + l15) * 32 + g * 8];
#pragma unroll
        for (int mi = 0; mi < 4; ++mi)
#pragma unroll
            for (int ni = 0; ni < 4; ++ni)
                acc[mi][ni] = __builtin_amdgcn_mfma_f32_16x16x32_bf16(af[mi], bq[ni], acc[mi][ni], 0, 0, 0);
        __syncthreads();
    }
#pragma unroll
    for (int mi = 0; mi < 4; ++mi)
#pragma unroll
        for (int ni = 0; ni < 4; ++ni)
#pragma unroll
            for (int r = 0; r < 4; ++r)
                o_mid[(size_t)(bm + wm + mi * 16 + g * 4 + r) * OD + h * 128 + wn + ni * 16 + l15] =
                    f2b(acc[mi][ni][r]);
}

// ---------------------------------------------------------------------------
// Fused rmsnorms + k_pe rope. Reads qkv f32; writes qanorm bf16, kfull bf16,
// ktT bf16 (kv-latent transposed, [512][T]). One block per row t.
// ---------------------------------------------------------------------------
__global__ __launch_bounds__(256) void norm_rope_kernel(
    const float* __restrict__ qkv, const float* __restrict__ qa_w,
    const float* __restrict__ kva_w, const int* __restrict__ positions,
    u16* __restrict__ qanorm, u16* __restrict__ kfull, u16* __restrict__ ktT)
{
    const int t = blockIdx.x, tid = threadIdx.x;
    const float* row = qkv + (size_t)t * QKV_N;
    float sq = 0.f, skv = 0.f;
    for (int i = tid; i < QL; i += 256)  { const float v = row[i];      sq  = fmaf(v, v, sq); }
    for (int i = tid; i < KVL; i += 256) { const float v = row[QL + i]; skv = fmaf(v, v, skv); }
#pragma unroll
    for (int off = 32; off >= 1; off >>= 1) {
        sq  += __shfl_down(sq, off, 64);
        skv += __shfl_down(skv, off, 64);
    }
    __shared__ float red[2][4];
    __shared__ float rs[2];
    const int wv = tid >> 6;
    if ((tid & 63) == 0) { red[0][wv] = sq; red[1][wv] = skv; }
    __syncthreads();
    if (tid == 0) {
        const float a = red[0][0] + red[0][1] + red[0][2] + red[0][3];
        const float b = red[1][0] + red[1][1] + red[1][2] + red[1][3];
        rs[0] = rsqrtf(a / (float)QL + 1e-6f);
        rs[1] = rsqrtf(b / (float)KVL + 1e-6f);
    }
    __syncthreads();
    const float rq = rs[0], rkv = rs[1];
    for (int i = tid; i < QL; i += 256)
        qanorm[(size_t)t * QL + i] = f2b(row[i] * rq * qa_w[i]);
    for (int i = tid; i < KVL; i += 256) {
        const u16 b = f2b(row[QL + i] * rkv * kva_w[i]);
        kfull[(size_t)t * KFULL + i] = b;
        ktT[(size_t)i * T_SEQ + t] = b;
    }
    if (tid < 32) {
        const float pos = (float)positions[t];
        const float inv = __expf(-(float)tid * ROPE_K);
        float s, c;
        __sincosf(pos * inv, &s, &c);
        const float x1 = row[QL + KVL + 2 * tid];
        const float x2 = row[QL + KVL + 2 * tid + 1];
        kfull[(size_t)t * KFULL + KVL + 2 * tid]     = f2b(x1 * c - x2 * s);
        kfull[(size_t)t * KFULL + KVL + 2 * tid + 1] = f2b(x2 * c + x1 * s);
    }
}

// ---------------------------------------------------------------------------
// Absorbed q_nope (f32 VALU), output bf16 pre-scaled: qf[h][t][l]
// ---------------------------------------------------------------------------
__global__ __launch_bounds__(256) void gemm_qnope_kernel(
    const float* __restrict__ q, const float* __restrict__ w_kvb,
    u16* __restrict__ qf)
{
    const int h = blockIdx.z;
    const int bn = blockIdx.x * 64;   // l
    const int bm = blockIdx.y * 64;   // t
    const int tid = threadIdx.x;
    __shared__ float As[16][68];
    __shared__ float Bs[16][68];
    const int tx = tid & 15, ty = tid >> 4;
    float acc[4][4];
#pragma unroll
    for (int i = 0; i < 4; ++i)
#pragma unroll
        for (int j = 0; j < 4; ++j) acc[i][j] = 0.f;

    const float* Abase = q + (size_t)bm * QB_N + h * (DN + DR);
    const float* Bbase = w_kvb + (size_t)bn * KVB_N + h * (DN + DV);
    const int row = tid >> 2, kq = (tid & 3) << 2;
    for (int k0 = 0; k0 < DN; k0 += 16) {
        {
            const float4 a4 = *(const float4*)(Abase + (size_t)row * QB_N + k0 + kq);
            As[kq + 0][row] = a4.x; As[kq + 1][row] = a4.y;
            As[kq + 2][row] = a4.z; As[kq + 3][row] = a4.w;
            const float4 b4 = *(const float4*)(Bbase + (size_t)row * KVB_N + k0 + kq);
            Bs[kq + 0][row] = b4.x; Bs[kq + 1][row] = b4.y;
            Bs[kq + 2][row] = b4.z; Bs[kq + 3][row] = b4.w;
        }
        __syncthreads();
#pragma unroll
        for (int kk = 0; kk < 16; ++kk) {
            float a[4], b[4];
            *(float4*)a = *(const float4*)(&As[kk][ty * 4]);
            *(float4*)b = *(const float4*)(&Bs[kk][tx * 4]);
#pragma unroll
            for (int i = 0; i < 4; ++i)
#pragma unroll
                for (int j = 0; j < 4; ++j)
                    acc[i][j] = fmaf(a[i], b[j], acc[i][j]);
        }
        __syncthreads();
    }
#pragma unroll
    for (int i = 0; i < 4; ++i)
#pragma unroll
        for (int j = 0; j < 4; ++j)
            qf[((size_t)h * T_SEQ + bm + ty * 4 + i) * KFULL + bn + tx * 4 + j] =
                f2b(acc[i][j] * SCALE_C);
}

// ---------------------------------------------------------------------------
// RoPE on q_pe -> qf[h][t][512:576] bf16, pre-scaled.
// ---------------------------------------------------------------------------
__global__ __launch_bounds__(256) void rope_qpe_kernel(
    const float* __restrict__ q, const int* __restrict__ positions,
    u16* __restrict__ qf)
{
    const int t = blockIdx.x, tid = threadIdx.x;
    const float pos = (float)positions[t];
    for (int p = tid; p < NH * 32; p += 256) {
        const int h = p >> 5, i = p & 31;
        const float inv = __expf(-(float)i * ROPE_K);
        float s, c;
        __sincosf(pos * inv, &s, &c);
        const float* src = q + (size_t)t * QB_N + h * (DN + DR) + DN;
        u16* dst = qf + ((size_t)h * T_SEQ + t) * KFULL + KVL;
        const float x1 = src[2 * i], x2 = src[2 * i + 1];
        dst[2 * i]     = f2b(SCALE_C * (x1 * c - x2 * s));
        dst[2 * i + 1] = f2b(SCALE_C * (x2 * c + x1 * s));
    }
}

// ---------------------------------------------------------------------------
// MFMA flash attention. Block = (64 q rows, 1 head), 4 waves x 16 q rows.
// qf (pre-scaled, bf16 [NH][T][576]); kfull bf16 [T][576]; ktT bf16 [512][T].
// o_lat bf16 [NH][T][512].
// Ks[32][584] and Vt[512][40] share one LDS buffer (phase-disjoint).
// ---------------------------------------------------------------------------
__global__ __launch_bounds__(256, 2) void attn_mfma(
    const u16* __restrict__ qf, const u16* __restrict__ kfull,
    const u16* __restrict__ ktT, u16* __restrict__ o_lat)
{
    __shared__ u16 kv_s[512 * 40];   // Ks view: [32][584] (36.9KB) / Vt view: [512][40] (40KB)
    __shared__ u16 pt_s[64 * 40];    // P tile, row stride 40
    const int h = blockIdx.y;
    const int qt0 = (int)(gridDim.x - 1 - blockIdx.x) * 64;   // heavy blocks first
    const int tid = threadIdx.x, lane = tid & 63, wave = tid >> 6;
    const int g = lane >> 4, l15 = lane & 15;

    const u16* qp = qf + ((size_t)h * T_SEQ + qt0 + wave * 16 + l15) * KFULL + g * 8;

    v4f acc[32];
#pragma unroll
    for (int v = 0; v < 32; ++v) acc[v] = (v4f){0.f, 0.f, 0.f, 0.f};
    float mr[4] = {-1e30f, -1e30f, -1e30f, -1e30f};
    float lr[4] = {0.f, 0.f, 0.f, 0.f};

    const int ksr = tid >> 3, ksc = tid & 7;   // Ks staging: 32 rows x 8 col-threads
    const int vsr = tid >> 2, vsc = tid & 3;   // Vt staging: 64 rows x 4 col-threads
    const int nk = qt0 / 32 + 2;

    for (int kt = 0; kt < nk; ++kt) {
        const int kt0 = kt * 32;
        // ---- stage K tile ----
        {
            const u16* src = kfull + (size_t)(kt0 + ksr) * KFULL + ksc * 8;
            u16* dst = kv_s + ksr * 584 + ksc * 8;
#pragma unroll
            for (int i = 0; i < 9; ++i)
                *(uint4*)(dst + i * 64) = *(const uint4*)(src + i * 64);
        }
        __syncthreads();
        // ---- S = Q K^T (two 16-key column tiles), K-dim 576 = 2x9x32 ----
        v4f s0 = (v4f){0.f, 0.f, 0.f, 0.f}, s1 = (v4f){0.f, 0.f, 0.f, 0.f};
#pragma unroll
        for (int half = 0; half < 2; ++half) {
            v8bf aq[9];
#pragma unroll
            for (int c = 0; c < 9; ++c)
                aq[c] = *(const v8bf*)(qp + (half * 9 + c) * 32);
#pragma unroll
            for (int c = 0; c < 9; ++c) {
                const int o = (half * 9 + c) * 32 + g * 8;
                v8bf b0 = *(const v8bf*)(kv_s + l15 * 584 + o);
                v8bf b1 = *(const v8bf*)(kv_s + (16 + l15) * 584 + o);
                s0 = __builtin_amdgcn_mfma_f32_16x16x32_bf16(aq[c], b0, s0, 0, 0, 0);
                s1 = __builtin_amdgcn_mfma_f32_16x16x32_bf16(aq[c], b1, s1, 0, 0, 0);
            }
        }
        __syncthreads();   // all waves done with Ks before Vt overwrites it
        // ---- stage V^T tile (overwrites Ks region) ----
        {
#pragma unroll
            for (int i = 0; i < 8; ++i) {
                const int v = vsr + i * 64;
                *(uint4*)(kv_s + v * 40 + vsc * 8) =
                    *(const uint4*)(ktT + (size_t)v * T_SEQ + kt0 + vsc * 8);
            }
        }
        // ---- online softmax (registers + shfl within 16-lane col group) ----
        {
            const int qr = qt0 + wave * 16 + g * 4;          // + r
            const int kc0 = kt0 + l15, kc1 = kt0 + 16 + l15;
            float sv0[4], sv1[4], mx[4], alpha[4], rsum[4];
#pragma unroll
            for (int r = 0; r < 4; ++r) {
                sv0[r] = (kc0 <= qr + r) ? s0[r] : -1e30f;
                sv1[r] = (kc1 <= qr + r) ? s1[r] : -1e30f;
                float v = fmaxf(sv0[r], sv1[r]);
                v = fmaxf(v, __shfl_xor(v, 1, 64));
                v = fmaxf(v, __shfl_xor(v, 2, 64));
                v = fmaxf(v, __shfl_xor(v, 4, 64));
                v = fmaxf(v, __shfl_xor(v, 8, 64));
                mx[r] = fmaxf(mr[r], v);
                alpha[r] = __expf(mr[r] - mx[r]);
                const float p0 = __expf(sv0[r] - mx[r]);
                const float p1 = __expf(sv1[r] - mx[r]);
                pt_s[(wave * 16 + g * 4 + r) * 40 + l15]      = f2b(p0);
                pt_s[(wave * 16 + g * 4 + r) * 40 + 16 + l15] = f2b(p1);
                float s = p0 + p1;
                s += __shfl_xor(s, 1, 64);
                s += __shfl_xor(s, 2, 64);
                s += __shfl_xor(s, 4, 64);
                s += __shfl_xor(s, 8, 64);
                rsum[r] = s;
                mr[r] = mx[r];
                lr[r] = lr[r] * alpha[r] + rsum[r];
            }
#pragma unroll
            for (int v = 0; v < 32; ++v) {
                acc[v][0] *= alpha[0]; acc[v][1] *= alpha[1];
                acc[v][2] *= alpha[2]; acc[v][3] *= alpha[3];
            }
        }
        __syncthreads();   // Vt + Pt visible
        // ---- O += P V ----
        {
            v8bf pf = *(const v8bf*)(pt_s + (wave * 16 + l15) * 40 + g * 8);
#pragma unroll
            for (int v = 0; v < 32; ++v) {
                v8bf vb = *(const v8bf*)(kv_s + (v * 16 + l15) * 40 + g * 8);
                acc[v] = __builtin_amdgcn_mfma_f32_16x16x32_bf16(pf, vb, acc[v], 0, 0, 0);
            }
        }
        __syncthreads();   // done with Vt before next Ks staging
    }
    // ---- normalize + store ----
    float linv[4] = {1.f / lr[0], 1.f / lr[1], 1.f / lr[2], 1.f / lr[3]};
    u16* op = o_lat + ((size_t)h * T_SEQ + qt0 + wave * 16 + g * 4) * 512 + l15;
#pragma unroll
    for (int v = 0; v < 32; ++v)
#pragma unroll
        for (int r = 0; r < 4; ++r)
            op[(size_t)r * 512 + v * 16] = f2b(acc[v][r] * linv[r]);
}

// ---------------------------------------------------------------------------
extern "C" void kernel_launch(void* const* d_in, const int* in_sizes, int n_in,
                              void* d_out, int out_size, void* d_ws, size_t ws_size,
                              hipStream_t stream)
{
    const int*   positions = (const int*)d_in[0];
    const float* hs        = (const float*)d_in[1];
    const float* w_fused   = (const float*)d_in[2];
    const float* w_qb      = (const float*)d_in[3];
    const float* w_kvb     = (const float*)d_in[4];
    const float* w_o       = (const float*)d_in[5];
    const float* qa_w      = (const float*)d_in[6];
    const float* kva_w     = (const float*)d_in[7];
    float* out = (float*)d_out;
    char*  ws  = (char*)d_ws;

    // workspace layout (bytes), with phase-disjoint aliasing:
    // R0 (38,010,880): [wfT 2176x5120 bf16][wqbT 3072x1536][qanorm 2048x1536]  -> later o_lat 16x2048x512
    // R1 (17,301,504): qkv f32 2048x2112                                       -> later o_mid 2048x2048 bf16
    // R2 (25,165,824): hs_bf 2048x5120 bf16 -> qmat f32 2048x3072 -> woT 5120x2048 bf16
    // R3: wvcT 16x128x512 bf16 | R4: kfull bf16 | R5: ktT bf16 | R6: qf bf16
    char* R0 = ws;
    char* R1 = R0 + 38010880;
    char* R2 = R1 + 17301504;
    char* R3 = R2 + 25165824;
    char* R4 = R3 + 2097152;
    char* R5 = R4 + 2359296;
    char* R6 = R5 + 2097152;     // R6 end = 124,780,544 bytes (< proven 134.7MB)

    u16*   wfT    = (u16*)R0;
    u16*   wqbT   = (u16*)(R0 + 22282240);
    u16*   qanorm = (u16*)(R0 + 31719424);
    u16*   o_lat  = (u16*)R0;
    float* qkv    = (float*)R1;
    u16*   o_mid  = (u16*)R1;
    u16*   hs_bf  = (u16*)R2;
    float* qmat   = (float*)R2;
    u16*   woT    = (u16*)R2;
    u16*   wvcT   = (u16*)R3;
    u16*   kfull  = (u16*)R4;
    u16*   ktT    = (u16*)R5;
    u16*   qf     = (u16*)R6;

    // 1. convert hs -> bf16
    cvt_bf16<<<(T_SEQ * HID / 4 + 255) / 256, 256, 0, stream>>>(hs, hs_bf, T_SEQ * HID / 4);
    // 2. transpose-convert w_fused -> wfT [2112(pad2176)][5120]
    transcvt<<<dim3(HID / 32, QKV_N / 32, 1), 256, 0, stream>>>(w_fused, wfT, QKV_N, 0, 0, 0, HID);
    // 3. qkv = hs @ w_fused   (f32 out)
    gemm_bt<<<dim3((QKV_N + 127) / 128, T_SEQ / 128), 256, 0, stream>>>(
        hs_bf, wfT, qkv, T_SEQ, QKV_N, HID);
    // 4. transpose-convert w_qb -> wqbT [3072][1536]
    transcvt<<<dim3(QL / 32, QB_N / 32, 1), 256, 0, stream>>>(w_qb, wqbT, QB_N, 0, 0, 0, QL);
    // 5. rmsnorms + k_pe rope -> qanorm bf16, kfull bf16, ktT bf16
    norm_rope_kernel<<<T_SEQ, 256, 0, stream>>>(qkv, qa_w, kva_w, positions, qanorm, kfull, ktT);
    // 6. qmat = qanorm @ w_qb  (f32 out; overwrites hs_bf region)
    gemm_bt<<<dim3(QB_N / 128, T_SEQ / 128), 256, 0, stream>>>(
        qanorm, wqbT, qmat, T_SEQ, QB_N, QL);
    // 7. absorbed q_nope + q_pe rope -> qf bf16 (pre-scaled)
    gemm_qnope_kernel<<<dim3(KVL / 64, T_SEQ / 64, NH), 256, 0, stream>>>(qmat, w_kvb, qf);
    rope_qpe_kernel<<<T_SEQ, 256, 0, stream>>>(qmat, positions, qf);
    // 8. wvcT[h][v][l] from w_kvb
    transcvt<<<dim3(KVL / 32, DV / 32, NH), 256, 0, stream>>>(
        w_kvb, wvcT, KVB_N, DN, DN + DV, (long)DV * KVL, KVL);
    // 9. MFMA flash attention -> o_lat bf16 (overwrites wfT/wqbT/qanorm)
    attn_mfma<<<dim3(T_SEQ / 64, NH), 256, 0, stream>>>(qf, kfull, ktT, o_lat);
    // 10. o_mid = per-head o_lat @ w_vc  (bf16 out; overwrites qkv)
    gemm_vc<<<dim3(T_SEQ / 128, NH), 256, 0, stream>>>(o_lat, wvcT, o_mid);
    // 11. transpose-convert w_o -> woT [5120][2048] (overwrites qmat)
    transcvt<<<dim3(OD / 32, HID / 32, 1), 256, 0, stream>>>(w_o, woT, HID, 0, 0, 0, OD);
    // 12. out = o_mid @ w_o  (f32 out)
    gemm_bt<<<dim3(HID / 128, T_SEQ / 128), 256, 0, stream>>>(
        o_mid, woT, out, T_SEQ, HID, OD);
}